// Round 4
// baseline (306.920 us; speedup 1.0000x reference)
//
#include <hip/hip_runtime.h>
#include <stdint.h>

#define DIM    680
#define DPAD   768      // 3 x 256 tiles
#define NCH    864      // 55296 / 64 g-chunks
#define NB_Q   24
#define SPLITS 36
#define STAGES 24       // NCH / SPLITS
#define NTILE  6        // upper-triangle 256x256 tiles of 3x3

typedef __bf16 bf16x8 __attribute__((ext_vector_type(8)));
typedef float  f32x16 __attribute__((ext_vector_type(16)));

typedef __attribute__((address_space(3))) unsigned       lds_u32;
typedef __attribute__((address_space(1))) const unsigned glb_u32;

__constant__ int c_tj[NTILE] = {0, 0, 0, 1, 1, 2};
__constant__ int c_ti[NTILE] = {0, 1, 2, 1, 2, 2};

static __device__ __forceinline__ unsigned f2bf(float x) {
    union { float f; unsigned u; } c; c.f = x;
    unsigned u = c.u;
    return (u + 0x7FFFu + ((u >> 16) & 1u)) >> 16;  // RNE
}

static __device__ __forceinline__ float bf2f(unsigned short h) {
    union { unsigned u; float f; } c; c.u = ((unsigned)h) << 16;
    return c.f;
}

// ---------------------------------------------------------------------------
// k1-v3: D (55296 x 680 fp32) -> Awt bf16 (scaled by sqrt(qw[b])), chunk-
//     transposed for k2's DMA. v3: double-buffered fp32 tile so chunk cc+1's
//     global_load_lds DMA flies under chunk cc's gather/convert/store phase
//     (v2 was DMA -> drain -> compute fully serial, 2 barriers/chunk).
//     One __syncthreads per chunk now: drains cc's DMA AND retires cc-1's
//     gather reads before cc+1's DMA overwrites that buffer.
// ---------------------------------------------------------------------------
__global__ __launch_bounds__(256) void k1_transpose(
        const float* __restrict__ D, const float* __restrict__ qw,
        uint4* __restrict__ awt) {
    __shared__ float sq[NB_Q];
    __shared__ float tile[2][4096];   // 2 x (64 rows x 64 cols) fp32, swizzled
    const int t   = threadIdx.x;
    const int cg0 = blockIdx.x * 4;
    const int i0  = blockIdx.y * 64;
    if (t < NB_Q) sq[t] = sqrtf(qw[t]);

    int  rowr[4], gcol[4];
    bool inb[4];
#pragma unroll
    for (int rd = 0; rd < 4; ++rd) {
        const int row = rd * 16 + (t >> 4);
        const int p   = row >> 3;
        const int sg  = (t & 15) ^ p;
        rowr[rd] = row;
        gcol[rd] = i0 + sg * 4;          // multiple of 4; 680%4==0 -> no straddle
        inb[rd]  = (gcol[rd] < DIM);
        if (!inb[rd]) {                  // zero once; OOB slots stay zero
            float4 z = {0.f, 0.f, 0.f, 0.f};
            *reinterpret_cast<float4*>(&tile[0][rd * 1024 + t * 4]) = z;
            *reinterpret_cast<float4*>(&tile[1][rd * 1024 + t * 4]) = z;
        }
    }

#define K1_STAGE(cc_, buf_)                                                   \
    do {                                                                      \
        const int g0_ = (cg0 + (cc_)) * 64;                                   \
        _Pragma("unroll")                                                     \
        for (int rd = 0; rd < 4; ++rd) {                                      \
            if (inb[rd]) {                                                    \
                __builtin_amdgcn_global_load_lds(                             \
                    (glb_u32*)(D + (size_t)(g0_ + rowr[rd]) * DIM + gcol[rd]),\
                    (lds_u32*)(&tile[(buf_)][rd * 1024 + t * 4]), 16, 0, 0);  \
            }                                                                 \
        }                                                                     \
    } while (0)

    __syncthreads();   // sq + zeros visible
    K1_STAGE(0, 0);

    for (int cc = 0; cc < 4; ++cc) {
        const int cur = cc & 1;
        const int cg  = cg0 + cc;
        const int g0  = cg * 64;
        __syncthreads();   // drains cc's DMA; retires cc-1's reads of buf cur^1
        if (cc + 1 < 4) K1_STAGE(cc + 1, cur ^ 1);   // flies under convert/store

#pragma unroll
        for (int s = 0; s < 2; ++s) {
            const int l  = t + s * 256;
            const int c  = l >> 3;       // local col 0..63
            const int kc = l & 7;        // 16B chunk within col
            unsigned h[8];
#pragma unroll
            for (int j = 0; j < 8; ++j) {
                const int row = kc * 8 + j;
                const float v = tile[cur][row * 64 + (((c >> 2) ^ kc) << 2) + (c & 3)];
                const int b = ((g0 + row) / 48) % 24;
                h[j] = f2bf(v * sq[b]);
            }
            uint4 o;
            o.x = h[0] | (h[1] << 16);
            o.y = h[2] | (h[3] << 16);
            o.z = h[4] | (h[5] << 16);
            o.w = h[6] | (h[7] << 16);
            const size_t slot = ((size_t)cg * DPAD + (size_t)(i0 + c)) * 8
                              + (size_t)(kc ^ (c & 7));
            awt[slot] = o;
        }
    }
#undef K1_STAGE
}

// ---------------------------------------------------------------------------
// kF: F (1024 x 680 fp32) -> Fb bf16 (1024 x 768, k-padded with zeros),
//     row-major. 768%8==0 and 680%8==0 -> clean uint4 (8 bf16) packing.
// ---------------------------------------------------------------------------
__global__ __launch_bounds__(256) void kf_conv(const float* __restrict__ F,
                                               uint4* __restrict__ Fb) {
    const int idx = blockIdx.x * 256 + threadIdx.x;   // 98304 uint4's
    const int row = idx / 96;                         // 768/8 = 96 per row
    const int c0  = (idx % 96) * 8;
    uint4 o = {0u, 0u, 0u, 0u};
    if (c0 < DIM) {
        const float4 a = *reinterpret_cast<const float4*>(F + (size_t)row * DIM + c0);
        const float4 b = *reinterpret_cast<const float4*>(F + (size_t)row * DIM + c0 + 4);
        o.x = f2bf(a.x) | (f2bf(a.y) << 16);
        o.y = f2bf(a.z) | (f2bf(a.w) << 16);
        o.z = f2bf(b.x) | (f2bf(b.y) << 16);
        o.w = f2bf(b.z) | (f2bf(b.w) << 16);
    }
    Fb[idx] = o;
}

// ---------------------------------------------------------------------------
// k2-v5: partial[split][tile] = sum over this split's 24 chunks of
//     A_band(tj)^T * A_band(ti), upper-triangle tiles only (M symmetric).
//     216 blocks (36 splits x 6 tiles, XCD-chunked swizzle), 512 thr = 8
//     waves (4m x 2n), wave tile 64x128, mfma_f32_32x32x16_bf16.
//     v5 vs v4: counted-vmcnt schedule (T4). v4's __syncthreads drained
//     vmcnt(0), force-completing the just-issued prefetch each stage ->
//     DMA window = MFMA phase only, HBM tails serialized x24. Now:
//        wait vmcnt(LD) ; s_barrier            // st resident, st+1 flying
//        ds_read + MFMA (setprio-wrapped)      // compute st
//        lgkmcnt(0) ; s_barrier                // buf st free on all waves
//        issue st+2 into buf st's slot         // window = full stage st+1
//     LD = per-wave loads of one stage (8 non-diag / 4 diag, uniform per
//     block). Loads stay in flight ACROSS barriers; no full drain in-loop.
// ---------------------------------------------------------------------------
__global__ __launch_bounds__(512) void k2_gram(const uint4* __restrict__ awt,
                                               uint2* __restrict__ parts) {
    __shared__ uint4 smA[2][2048];   // 256 cols x 8 slots (swizzled), 2x32 KB
    __shared__ uint4 smB[2][2048];
    const int t  = threadIdx.x;
    // HW round-robins linear block id over 8 XCDs; remap so each XCD gets a
    // contiguous run of 27 logical ids -> same-split tiles share an L2.
    const int h       = blockIdx.x;              // 0..215
    const int logical = (h & 7) * 27 + (h >> 3); // bijective (216 = 8*27)
    const int split   = logical / 6;
    const int t6      = logical % 6;
    const int tj    = c_tj[t6];   // row band of M
    const int ti    = c_ti[t6];   // col band of M
    const bool diag = (tj == ti);
    const int wave  = t >> 6;
    const int lane  = t & 63;
    const int wm    = wave & 3;   // m: 64-row band
    const int wn    = wave >> 2;  // n: 128-col band
    const int cl    = lane & 31;
    const int half  = lane >> 5;

    f32x16 acc[2][4];
    const f32x16 zero = {};
#pragma unroll
    for (int a = 0; a < 2; ++a)
#pragma unroll
        for (int b = 0; b < 4; ++b) acc[a][b] = zero;

#define K2_STAGE(st_, buf_)                                                   \
    do {                                                                      \
        const int    cg_ = split * STAGES + (st_);                            \
        const size_t bA_ = ((size_t)cg_ * DPAD + tj * 256) * 8;               \
        _Pragma("unroll")                                                     \
        for (int j = 0; j < 4; ++j) {                                         \
            __builtin_amdgcn_global_load_lds(                                 \
                (glb_u32*)(awt + bA_ + j * 512 + t),                          \
                (lds_u32*)(&smA[(buf_)][j * 512 + t]), 16, 0, 0);             \
        }                                                                     \
        if (!diag) {                                                          \
            const size_t bB_ = ((size_t)cg_ * DPAD + ti * 256) * 8;           \
            _Pragma("unroll")                                                 \
            for (int j = 0; j < 4; ++j) {                                     \
                __builtin_amdgcn_global_load_lds(                             \
                    (glb_u32*)(awt + bB_ + j * 512 + t),                      \
                    (lds_u32*)(&smB[(buf_)][j * 512 + t]), 16, 0, 0);         \
            }                                                                 \
        }                                                                     \
    } while (0)

    K2_STAGE(0, 0);
    K2_STAGE(1, 1);

    for (int st = 0; st < STAGES; ++st) {
        const int cur = st & 1;
        // st's tile resident (only st+1's LD loads may remain in flight).
        // vmcnt is per-wave, in-order; every wave issues the same LD/stage.
        if (st + 1 < STAGES) {
            if (diag) asm volatile("s_waitcnt vmcnt(4)" ::: "memory");
            else      asm volatile("s_waitcnt vmcnt(8)" ::: "memory");
        } else {
            asm volatile("s_waitcnt vmcnt(0)" ::: "memory");
        }
        __builtin_amdgcn_s_barrier();   // all waves' slices of st resident

        const bf16x8* pA = reinterpret_cast<const bf16x8*>(smA[cur]);
        const bf16x8* pB = diag ? pA : reinterpret_cast<const bf16x8*>(smB[cur]);
#pragma unroll
        for (int t4 = 0; t4 < 4; ++t4) {          // K = 64 per stage, 16/mfma
            const int kc = 2 * t4 + half;
            bf16x8 af[2], bfr[4];
#pragma unroll
            for (int ms = 0; ms < 2; ++ms) {
                const int col = wm * 64 + ms * 32 + cl;
                af[ms] = pA[col * 8 + (kc ^ (col & 7))];
            }
#pragma unroll
            for (int ns = 0; ns < 4; ++ns) {
                const int col = wn * 128 + ns * 32 + cl;
                bfr[ns] = pB[col * 8 + (kc ^ (col & 7))];
            }
            __builtin_amdgcn_s_setprio(1);
#pragma unroll
            for (int ms = 0; ms < 2; ++ms)
#pragma unroll
                for (int ns = 0; ns < 4; ++ns)
                    acc[ms][ns] = __builtin_amdgcn_mfma_f32_32x32x16_bf16(
                        af[ms], bfr[ns], acc[ms][ns], 0, 0, 0);
            __builtin_amdgcn_s_setprio(0);
        }
        asm volatile("s_waitcnt lgkmcnt(0)" ::: "memory");  // my reads done
        __builtin_amdgcn_s_barrier();   // everyone's reads done -> buf free
        if (st + 2 < STAGES) K2_STAGE(st + 2, cur);  // window = full stage st+1
    }
#undef K2_STAGE

    // row-quad packed bf16 stores: full-line coalesced, no atomics
    uint2* pt = parts + (size_t)(split * NTILE + t6) * 16384;
#pragma unroll
    for (int ms = 0; ms < 2; ++ms) {
        const int rowb = wm * 64 + ms * 32 + 4 * half;   // multiple of 4
#pragma unroll
        for (int ns = 0; ns < 4; ++ns) {
            const int colt = wn * 128 + ns * 32 + cl;
#pragma unroll
            for (int q = 0; q < 4; ++q) {                // rows rowb+8q .. +3
                uint2 w;
                w.x = f2bf(acc[ms][ns][q * 4 + 0]) | (f2bf(acc[ms][ns][q * 4 + 1]) << 16);
                w.y = f2bf(acc[ms][ns][q * 4 + 2]) | (f2bf(acc[ms][ns][q * 4 + 3]) << 16);
                pt[(size_t)(((rowb >> 2) + 2 * q) * 256 + colt)] = w;
            }
        }
    }
}

// ---------------------------------------------------------------------------
// k2r-v2: Mb[768x768 bf16] = sum over 36 split-partials per tile, + mirror.
//     Writes bf16 directly in k3's operand format (M is symmetric, so
//     row-major Mb serves as both M and M^T). No fp32 M anymore.
// ---------------------------------------------------------------------------
__global__ __launch_bounds__(256) void k2_reduce(
        const uint2* __restrict__ parts, unsigned short* __restrict__ Mb) {
    const int t6 = blockIdx.y;
    const int tj = c_tj[t6];
    const int ti = c_ti[t6];
    const int idx4 = blockIdx.x * 256 + threadIdx.x;   // uint4 index, 8192/tile
    const int w0 = idx4 * 2;
    const int quad = w0 >> 8;
    const int c = w0 & 255;                            // even
    float s[8] = {0.f, 0.f, 0.f, 0.f, 0.f, 0.f, 0.f, 0.f};
    const uint4* base = reinterpret_cast<const uint4*>(parts) + idx4;
#pragma unroll 4
    for (int sp = 0; sp < SPLITS; ++sp) {
        const uint4 u = base[(size_t)(sp * NTILE + t6) * 8192];
        s[0] += bf2f((unsigned short)(u.x & 0xFFFF));
        s[1] += bf2f((unsigned short)(u.x >> 16));
        s[2] += bf2f((unsigned short)(u.y & 0xFFFF));
        s[3] += bf2f((unsigned short)(u.y >> 16));
        s[4] += bf2f((unsigned short)(u.z & 0xFFFF));
        s[5] += bf2f((unsigned short)(u.z >> 16));
        s[6] += bf2f((unsigned short)(u.w & 0xFFFF));
        s[7] += bf2f((unsigned short)(u.w >> 16));
    }
    const int R = tj * 256 + 4 * quad;
    const int C = ti * 256 + c;
#pragma unroll
    for (int i = 0; i < 4; ++i) {      // rows R..R+3, cols C,C+1
        const unsigned w = f2bf(s[i]) | (f2bf(s[4 + i]) << 16);
        *reinterpret_cast<unsigned*>(Mb + (size_t)(R + i) * DPAD + C) = w;
    }
    if (ti != tj) {                    // mirror: rows C,C+1, cols R..R+3
        uint2 m0, m1;
        m0.x = f2bf(s[0]) | (f2bf(s[1]) << 16);
        m0.y = f2bf(s[2]) | (f2bf(s[3]) << 16);
        m1.x = f2bf(s[4]) | (f2bf(s[5]) << 16);
        m1.y = f2bf(s[6]) | (f2bf(s[7]) << 16);
        *reinterpret_cast<uint2*>(Mb + (size_t)(C + 0) * DPAD + R) = m0;
        *reinterpret_cast<uint2*>(Mb + (size_t)(C + 1) * DPAD + R) = m1;
    }
}

// ---------------------------------------------------------------------------
// k3-v2: out(1024 x 680) = F @ M via bf16 MFMA, full K=768 (no split-K, no
//     reduce kernel, no fp32 partial round-trip). Operands Fb/Mb are bf16
//     row-major with rows = contiguous K runs (M symmetric -> rows==cols).
//     1 wave / block, 64x64 output tile, grid (16, 11) = 176 blocks; both
//     operands (~2.7 MB) are L2-resident. Staging: global_load_lds with
//     source-side XOR pre-swizzle (LDS dest is forced lane-linear),
//     double-buffered with counted vmcnt(16) (single-wave => explicit
//     waitcnt instead of __syncthreads, which could be elided).
// ---------------------------------------------------------------------------
__global__ __launch_bounds__(64) void k3_mfma(const uint4* __restrict__ Fb,
                                              const uint4* __restrict__ Mb,
                                              float* __restrict__ out) {
    __shared__ uint4 sA[2][512];   // 64 cols x 8 k-chunks, swizzled, 2x8 KB
    __shared__ uint4 sB[2][512];
    const int t    = threadIdx.x;   // 0..63
    const int n0   = blockIdx.x * 64;
    const int i0   = blockIdx.y * 64;
    const int cl   = t & 31;
    const int half = t >> 5;

    f32x16 acc[2][2];
    const f32x16 zero = {};
    acc[0][0] = zero; acc[0][1] = zero; acc[1][0] = zero; acc[1][1] = zero;

    // load j, lane t -> LDS slot j*64+t == (n_loc, kcs) with n_loc=j*8+(t>>3),
    // kcs=t&7; source chunk pre-swizzled so slot (col, kc^(col&7)) holds kc.
#define K3_STAGE(ck_, buf_)                                                   \
    do {                                                                      \
        const int kcs_ = t & 7;                                               \
        _Pragma("unroll")                                                     \
        for (int j = 0; j < 8; ++j) {                                         \
            const int nl_ = j * 8 + (t >> 3);                                 \
            const int sc_ = (ck_) * 8 + (kcs_ ^ (nl_ & 7));                   \
            __builtin_amdgcn_global_load_lds(                                 \
                (glb_u32*)(Fb + (size_t)(n0 + nl_) * 96 + sc_),               \
                (lds_u32*)(&sA[(buf_)][j * 64 + t]), 16, 0, 0);               \
            __builtin_amdgcn_global_load_lds(                                 \
                (glb_u32*)(Mb + (size_t)(i0 + nl_) * 96 + sc_),               \
                (lds_u32*)(&sB[(buf_)][j * 64 + t]), 16, 0, 0);               \
        }                                                                     \
    } while (0)

    K3_STAGE(0, 0);
    asm volatile("s_waitcnt vmcnt(0)" ::: "memory");

    for (int ck = 0; ck < 12; ++ck) {          // K = 768 = 12 x 64
        const int cur = ck & 1;
        if (ck + 1 < 12) {
            // prior ds_reads of buf cur^1 completed (consumed by ck-1 MFMAs)
            asm volatile("s_waitcnt lgkmcnt(0)" ::: "memory");
            K3_STAGE(ck + 1, cur ^ 1);
            asm volatile("s_waitcnt vmcnt(16)" ::: "memory");  // cur's 16 done
        }
        const bf16x8* pA = reinterpret_cast<const bf16x8*>(sA[cur]);
        const bf16x8* pB = reinterpret_cast<const bf16x8*>(sB[cur]);
#pragma unroll
        for (int t4 = 0; t4 < 4; ++t4) {
            const int kc = 2 * t4 + half;
            bf16x8 af[2], bv[2];
#pragma unroll
            for (int ms = 0; ms < 2; ++ms) {
                const int col = ms * 32 + cl;
                af[ms] = pA[col * 8 + (kc ^ (col & 7))];
            }
#pragma unroll
            for (int ns = 0; ns < 2; ++ns) {
                const int col = ns * 32 + cl;
                bv[ns] = pB[col * 8 + (kc ^ (col & 7))];
            }
#pragma unroll
            for (int ms = 0; ms < 2; ++ms)
#pragma unroll
                for (int ns = 0; ns < 2; ++ns)
                    acc[ms][ns] = __builtin_amdgcn_mfma_f32_32x32x16_bf16(
                        af[ms], bv[ns], acc[ms][ns], 0, 0, 0);
        }
    }
#undef K3_STAGE

    // C layout (32x32): col = lane&31, row = (reg&3) + 8*(reg>>2) + 4*half
#pragma unroll
    for (int ms = 0; ms < 2; ++ms) {
        const int rowb = ms * 32 + 4 * half;
#pragma unroll
        for (int ns = 0; ns < 2; ++ns) {
            const int col = i0 + ns * 32 + cl;
            if (col < DIM) {
#pragma unroll
                for (int q = 0; q < 4; ++q)
#pragma unroll
                    for (int j = 0; j < 4; ++j)
                        out[(size_t)(n0 + rowb + 8 * q + j) * DIM + col]
                            = acc[ms][ns][4 * q + j];
            }
        }
    }
}

extern "C" void kernel_launch(void* const* d_in, const int* in_sizes, int n_in,
                              void* d_out, int out_size, void* d_ws, size_t ws_size,
                              hipStream_t stream) {
    const float* F  = (const float*)d_in[0];   // (1024, 680)
    const float* D  = (const float*)d_in[1];   // (48, 24, 48, 680)
    const float* qw = (const float*)d_in[2];   // (24,)
    float* out = (float*)d_out;
    char*  ws  = (char*)d_ws;

    uint4* awt = (uint4*)ws;                                    // 81.0 MiB bf16
    const size_t awt_bytes = (size_t)NCH * DPAD * 64 * 2;       // 84,934,656
    uint2* parts = (uint2*)(ws + awt_bytes);                    // 27.0 MiB bf16
    const size_t parts_bytes = (size_t)SPLITS * NTILE * 16384 * 8;  // 28,311,552
    unsigned short* Mb = (unsigned short*)(ws + awt_bytes + parts_bytes);  // 1.125 MiB
    const size_t mb_bytes = (size_t)DPAD * DPAD * 2;            // 1,179,648
    uint4* Fb = (uint4*)(ws + awt_bytes + parts_bytes + mb_bytes);  // 1.5 MiB

    k1_transpose<<<dim3(NCH / 4, DPAD / 64), 256, 0, stream>>>(D, qw, awt);
    kf_conv<<<dim3(1024 * DPAD / 8 / 256), 256, 0, stream>>>(F, Fb);
    k2_gram<<<dim3(SPLITS * NTILE), 512, 0, stream>>>(awt, parts);
    k2_reduce<<<dim3(32, NTILE), 256, 0, stream>>>(parts, Mb);
    k3_mfma<<<dim3(16, 11), 64, 0, stream>>>(Fb, (const uint4*)Mb, out);
}

// Round 5
// 292.511 us; speedup vs baseline: 1.0493x; 1.0493x over previous
//
#include <hip/hip_runtime.h>
#include <stdint.h>

#define DIM    680
#define DPAD   768      // 3 x 256 tiles
#define NB_Q   24
#define SPLITS 36
#define STAGES 24       // 864 g-chunks / SPLITS
#define NTILE  6        // upper-triangle 256x256 tiles of 3x3

typedef __bf16 bf16x8 __attribute__((ext_vector_type(8)));
typedef float  f32x16 __attribute__((ext_vector_type(16)));

typedef __attribute__((address_space(3))) unsigned       lds_u32;
typedef __attribute__((address_space(1))) const unsigned glb_u32;

__constant__ int c_tj[NTILE] = {0, 0, 0, 1, 1, 2};
__constant__ int c_ti[NTILE] = {0, 1, 2, 1, 2, 2};

static __device__ __forceinline__ unsigned f2bf(float x) {
    union { float f; unsigned u; } c; c.f = x;
    unsigned u = c.u;
    return (u + 0x7FFFu + ((u >> 16) & 1u)) >> 16;  // RNE
}

static __device__ __forceinline__ float bf2f(unsigned short h) {
    union { unsigned u; float f; } c; c.u = ((unsigned)h) << 16;
    return c.f;
}

// ---------------------------------------------------------------------------
// k12 (fused k1+k2): parts[split][tile] = sum over the split's 24 chunks of
//     A_band(tj)^T * A_band(ti), where A = D scaled by sqrt(qw[beta(g)]) in
//     bf16 -- computed ON THE FLY from fp32 D, no awt intermediate.
//     Eliminates the 85 MB awt write + 243 MB awt re-read of the k1->k2
//     pipeline (R3/R4 schedule polish was neutral => traffic-bound).
//
//     216 blocks (36 splits x 6 tiles, XCD-chunked swizzle), 512 threads =
//     8 waves (4m x 2n), wave tile 64x128, mfma_f32_32x32x16_bf16.
//
//     Staging (per stage = one 64-g chunk): thread t owns band-column
//     cl_ = t&255, kc-half hg = t>>8. It loads its 32 fp32 elements
//     (rows hg*32..+31 of its column; wave-coalesced: 64 lanes = 256 B
//     contiguous per row), converts+scales in registers, and ds_writes
//     bf16x8 slots in the SAME XOR-swizzled layout the MFMA gather uses:
//     slot(col, kc) = col*8 + (kc ^ (col&7)).  Next-stage loads are issued
//     right after each convert (T14 issue-early/use-late): they fly across
//     ds_writes + barrier + MFMA; the compiler's auto-vmcnt at the next
//     convert's first reg use is the precise wait.  Raw s_barrier +
//     lgkmcnt(0) only -- __syncthreads would drain vmcnt(0) and kill the
//     prefetch.  Single-buffer LDS (64 KB): conv(st+1) overwrites only
//     after the post-MFMA barrier of st.
//
//     Scale: b(g) = (g/48)%24; per 8-row group one div + boundary select
//     (group crosses a /48 boundary at most once); sq[] reads are
//     wave-uniform (g is uniform per group) => LDS broadcast, free.
//     Pad cols (i >= 680): loads clamped to col 679 (keeps per-wave VMEM
//     counts uniform), packed value forced to 0.
// ---------------------------------------------------------------------------
__global__ __launch_bounds__(512) void k12_gram(const float* __restrict__ D,
                                                const float* __restrict__ qw,
                                                uint2* __restrict__ parts) {
    __shared__ float sq[NB_Q];
    __shared__ uint4 smA[2048];   // 256 cols x 8 slots (swizzled), 32 KB
    __shared__ uint4 smB[2048];
    const int t  = threadIdx.x;
    const int h       = blockIdx.x;              // 0..215
    const int logical = (h & 7) * 27 + (h >> 3); // bijective (216 = 8*27)
    const int split   = logical / 6;
    const int t6      = logical % 6;
    const int tj    = c_tj[t6];   // row band of M
    const int ti    = c_ti[t6];   // col band of M
    const bool diag = (tj == ti);
    // staging mapping
    const int cl_ = t & 255;      // column within band
    const int hg  = t >> 8;       // kc half: kc = hg*4 + 0..3
    const int cA  = tj * 256 + cl_;
    const int cB  = ti * 256 + cl_;
    const bool vA = (cA < DIM);
    const bool vB = (cB < DIM);
    const int cAc = vA ? cA : (DIM - 1);   // clamp: uniform VMEM counts
    const int cBc = vB ? cB : (DIM - 1);
    // MFMA mapping
    const int wave  = t >> 6;
    const int lane  = t & 63;
    const int wm    = wave & 3;   // m: 64-row band
    const int wn    = wave >> 2;  // n: 128-col band
    const int cl    = lane & 31;
    const int half  = lane >> 5;

    f32x16 acc[2][4];
    const f32x16 zero = {};
#pragma unroll
    for (int a = 0; a < 2; ++a)
#pragma unroll
        for (int b = 0; b < 4; ++b) acc[a][b] = zero;

    float ra[32], rb[32];   // staged fp32 (static indexing only)

#define K12_LOAD(reg_, st_, csrc_)                                            \
    do {                                                                      \
        const int g0_ = (split * STAGES + (st_)) * 64 + hg * 32;              \
        _Pragma("unroll")                                                     \
        for (int u_ = 0; u_ < 32; ++u_)                                       \
            reg_[u_] = D[(size_t)(g0_ + u_) * DIM + (csrc_)];                 \
    } while (0)

#define K12_CONV(reg_, valid_, sm_, st_)                                      \
    do {                                                                      \
        const int gg_ = (split * STAGES + (st_)) * 64 + hg * 32;              \
        _Pragma("unroll")                                                     \
        for (int kcg_ = 0; kcg_ < 4; ++kcg_) {                                \
            const int G_ = gg_ + kcg_ * 8;                                    \
            const int q_ = G_ / 48;                                           \
            const int r_ = G_ - q_ * 48;                                      \
            const float s0_ = sq[q_ % 24];                                    \
            const float s1_ = sq[(q_ + 1) % 24];                              \
            unsigned hh_[8];                                                  \
            _Pragma("unroll")                                                 \
            for (int j_ = 0; j_ < 8; ++j_) {                                  \
                const float sc_ = (r_ + j_ < 48) ? s0_ : s1_;                 \
                hh_[j_] = (valid_) ? f2bf(reg_[kcg_ * 8 + j_] * sc_) : 0u;    \
            }                                                                 \
            uint4 o_;                                                         \
            o_.x = hh_[0] | (hh_[1] << 16);                                   \
            o_.y = hh_[2] | (hh_[3] << 16);                                   \
            o_.z = hh_[4] | (hh_[5] << 16);                                   \
            o_.w = hh_[6] | (hh_[7] << 16);                                   \
            sm_[cl_ * 8 + ((hg * 4 + kcg_) ^ (cl_ & 7))] = o_;                \
        }                                                                     \
    } while (0)

    // prologue: stage-0 loads fly while sq is set up
    K12_LOAD(ra, 0, cAc);
    if (!diag) K12_LOAD(rb, 0, cBc);
    if (t < NB_Q) sq[t] = sqrtf(qw[t]);
    asm volatile("s_waitcnt lgkmcnt(0)" ::: "memory");
    __builtin_amdgcn_s_barrier();   // sq visible (vmcnt untouched)

    for (int st = 0; st < STAGES; ++st) {
        // convert st (compiler emits the precise vmcnt wait for ra/rb here),
        // then immediately issue st+1's loads: they fly across the ds_writes,
        // barrier, and the whole MFMA phase.
        K12_CONV(ra, vA, smA, st);
        if (st + 1 < STAGES) K12_LOAD(ra, st + 1, cAc);
        if (!diag) {
            K12_CONV(rb, vB, smB, st);
            if (st + 1 < STAGES) K12_LOAD(rb, st + 1, cBc);
        }
        asm volatile("s_waitcnt lgkmcnt(0)" ::: "memory");  // my ds_writes done
        __builtin_amdgcn_s_barrier();   // tiles complete for all waves

        const bf16x8* pA = reinterpret_cast<const bf16x8*>(smA);
        const bf16x8* pB = diag ? pA : reinterpret_cast<const bf16x8*>(smB);
#pragma unroll
        for (int t4 = 0; t4 < 4; ++t4) {          // K = 64 per stage, 16/mfma
            const int kc = 2 * t4 + half;
            bf16x8 af[2], bfr[4];
#pragma unroll
            for (int ms = 0; ms < 2; ++ms) {
                const int col = wm * 64 + ms * 32 + cl;
                af[ms] = pA[col * 8 + (kc ^ (col & 7))];
            }
#pragma unroll
            for (int ns = 0; ns < 4; ++ns) {
                const int col = wn * 128 + ns * 32 + cl;
                bfr[ns] = pB[col * 8 + (kc ^ (col & 7))];
            }
            __builtin_amdgcn_s_setprio(1);
#pragma unroll
            for (int ms = 0; ms < 2; ++ms)
#pragma unroll
                for (int ns = 0; ns < 4; ++ns)
                    acc[ms][ns] = __builtin_amdgcn_mfma_f32_32x32x16_bf16(
                        af[ms], bfr[ns], acc[ms][ns], 0, 0, 0);
            __builtin_amdgcn_s_setprio(0);
        }
        asm volatile("s_waitcnt lgkmcnt(0)" ::: "memory");  // my frag reads done
        __builtin_amdgcn_s_barrier();   // all reads done -> tiles reusable
    }
#undef K12_LOAD
#undef K12_CONV

    // row-quad packed bf16 stores: full-line coalesced, no atomics
    uint2* pt = parts + (size_t)(split * NTILE + t6) * 16384;
#pragma unroll
    for (int ms = 0; ms < 2; ++ms) {
        const int rowb = wm * 64 + ms * 32 + 4 * half;   // multiple of 4
#pragma unroll
        for (int ns = 0; ns < 4; ++ns) {
            const int colt = wn * 128 + ns * 32 + cl;
#pragma unroll
            for (int q = 0; q < 4; ++q) {                // rows rowb+8q .. +3
                uint2 w;
                w.x = f2bf(acc[ms][ns][q * 4 + 0]) | (f2bf(acc[ms][ns][q * 4 + 1]) << 16);
                w.y = f2bf(acc[ms][ns][q * 4 + 2]) | (f2bf(acc[ms][ns][q * 4 + 3]) << 16);
                pt[(size_t)(((rowb >> 2) + 2 * q) * 256 + colt)] = w;
            }
        }
    }
}

// ---------------------------------------------------------------------------
// kF: F (1024 x 680 fp32) -> Fb bf16 (1024 x 768, k-padded with zeros),
//     row-major. 768%8==0 and 680%8==0 -> clean uint4 (8 bf16) packing.
// ---------------------------------------------------------------------------
__global__ __launch_bounds__(256) void kf_conv(const float* __restrict__ F,
                                               uint4* __restrict__ Fb) {
    const int idx = blockIdx.x * 256 + threadIdx.x;   // 98304 uint4's
    const int row = idx / 96;                         // 768/8 = 96 per row
    const int c0  = (idx % 96) * 8;
    uint4 o = {0u, 0u, 0u, 0u};
    if (c0 < DIM) {
        const float4 a = *reinterpret_cast<const float4*>(F + (size_t)row * DIM + c0);
        const float4 b = *reinterpret_cast<const float4*>(F + (size_t)row * DIM + c0 + 4);
        o.x = f2bf(a.x) | (f2bf(a.y) << 16);
        o.y = f2bf(a.z) | (f2bf(a.w) << 16);
        o.z = f2bf(b.x) | (f2bf(b.y) << 16);
        o.w = f2bf(b.z) | (f2bf(b.w) << 16);
    }
    Fb[idx] = o;
}

// ---------------------------------------------------------------------------
// k2r: Mb[768x768 bf16] = sum over 36 split-partials per tile, + mirror.
//     Writes bf16 directly in k3's operand format (M symmetric ->
//     row-major Mb serves as both M and M^T).
// ---------------------------------------------------------------------------
__global__ __launch_bounds__(256) void k2_reduce(
        const uint2* __restrict__ parts, unsigned short* __restrict__ Mb) {
    const int t6 = blockIdx.y;
    const int tj = c_tj[t6];
    const int ti = c_ti[t6];
    const int idx4 = blockIdx.x * 256 + threadIdx.x;   // uint4 index, 8192/tile
    const int w0 = idx4 * 2;
    const int quad = w0 >> 8;
    const int c = w0 & 255;                            // even
    float s[8] = {0.f, 0.f, 0.f, 0.f, 0.f, 0.f, 0.f, 0.f};
    const uint4* base = reinterpret_cast<const uint4*>(parts) + idx4;
#pragma unroll 4
    for (int sp = 0; sp < SPLITS; ++sp) {
        const uint4 u = base[(size_t)(sp * NTILE + t6) * 8192];
        s[0] += bf2f((unsigned short)(u.x & 0xFFFF));
        s[1] += bf2f((unsigned short)(u.x >> 16));
        s[2] += bf2f((unsigned short)(u.y & 0xFFFF));
        s[3] += bf2f((unsigned short)(u.y >> 16));
        s[4] += bf2f((unsigned short)(u.z & 0xFFFF));
        s[5] += bf2f((unsigned short)(u.z >> 16));
        s[6] += bf2f((unsigned short)(u.w & 0xFFFF));
        s[7] += bf2f((unsigned short)(u.w >> 16));
    }
    const int R = tj * 256 + 4 * quad;
    const int C = ti * 256 + c;
#pragma unroll
    for (int i = 0; i < 4; ++i) {      // rows R..R+3, cols C,C+1
        const unsigned w = f2bf(s[i]) | (f2bf(s[4 + i]) << 16);
        *reinterpret_cast<unsigned*>(Mb + (size_t)(R + i) * DPAD + C) = w;
    }
    if (ti != tj) {                    // mirror: rows C,C+1, cols R..R+3
        uint2 m0, m1;
        m0.x = f2bf(s[0]) | (f2bf(s[1]) << 16);
        m0.y = f2bf(s[2]) | (f2bf(s[3]) << 16);
        m1.x = f2bf(s[4]) | (f2bf(s[5]) << 16);
        m1.y = f2bf(s[6]) | (f2bf(s[7]) << 16);
        *reinterpret_cast<uint2*>(Mb + (size_t)(C + 0) * DPAD + R) = m0;
        *reinterpret_cast<uint2*>(Mb + (size_t)(C + 1) * DPAD + R) = m1;
    }
}

// ---------------------------------------------------------------------------
// k3: out(1024 x 680) = F @ M via bf16 MFMA, full K=768. Operands Fb/Mb are
//     bf16 row-major with rows = contiguous K runs (M symmetric).
//     1 wave / block, 64x64 tile, grid (16, 11); operands L2/L3-resident.
//     global_load_lds with source-side XOR pre-swizzle, double-buffered
//     with counted vmcnt(16).
// ---------------------------------------------------------------------------
__global__ __launch_bounds__(64) void k3_mfma(const uint4* __restrict__ Fb,
                                              const uint4* __restrict__ Mb,
                                              float* __restrict__ out) {
    __shared__ uint4 sA[2][512];   // 64 cols x 8 k-chunks, swizzled, 2x8 KB
    __shared__ uint4 sB[2][512];
    const int t    = threadIdx.x;   // 0..63
    const int n0   = blockIdx.x * 64;
    const int i0   = blockIdx.y * 64;
    const int cl   = t & 31;
    const int half = t >> 5;

    f32x16 acc[2][2];
    const f32x16 zero = {};
    acc[0][0] = zero; acc[0][1] = zero; acc[1][0] = zero; acc[1][1] = zero;

#define K3_STAGE(ck_, buf_)                                                   \
    do {                                                                      \
        const int kcs_ = t & 7;                                               \
        _Pragma("unroll")                                                     \
        for (int j = 0; j < 8; ++j) {                                         \
            const int nl_ = j * 8 + (t >> 3);                                 \
            const int sc_ = (ck_) * 8 + (kcs_ ^ (nl_ & 7));                   \
            __builtin_amdgcn_global_load_lds(                                 \
                (glb_u32*)(Fb + (size_t)(n0 + nl_) * 96 + sc_),               \
                (lds_u32*)(&sA[(buf_)][j * 64 + t]), 16, 0, 0);               \
            __builtin_amdgcn_global_load_lds(                                 \
                (glb_u32*)(Mb + (size_t)(i0 + nl_) * 96 + sc_),               \
                (lds_u32*)(&sB[(buf_)][j * 64 + t]), 16, 0, 0);               \
        }                                                                     \
    } while (0)

    K3_STAGE(0, 0);
    asm volatile("s_waitcnt vmcnt(0)" ::: "memory");

    for (int ck = 0; ck < 12; ++ck) {          // K = 768 = 12 x 64
        const int cur = ck & 1;
        if (ck + 1 < 12) {
            asm volatile("s_waitcnt lgkmcnt(0)" ::: "memory");
            K3_STAGE(ck + 1, cur ^ 1);
            asm volatile("s_waitcnt vmcnt(16)" ::: "memory");  // cur's 16 done
        }
        const bf16x8* pA = reinterpret_cast<const bf16x8*>(sA[cur]);
        const bf16x8* pB = reinterpret_cast<const bf16x8*>(sB[cur]);
#pragma unroll
        for (int t4 = 0; t4 < 4; ++t4) {
            const int kc = 2 * t4 + half;
            bf16x8 af[2], bv[2];
#pragma unroll
            for (int ms = 0; ms < 2; ++ms) {
                const int col = ms * 32 + cl;
                af[ms] = pA[col * 8 + (kc ^ (col & 7))];
            }
#pragma unroll
            for (int ns = 0; ns < 2; ++ns) {
                const int col = ns * 32 + cl;
                bv[ns] = pB[col * 8 + (kc ^ (col & 7))];
            }
#pragma unroll
            for (int ms = 0; ms < 2; ++ms)
#pragma unroll
                for (int ns = 0; ns < 2; ++ns)
                    acc[ms][ns] = __builtin_amdgcn_mfma_f32_32x32x16_bf16(
                        af[ms], bv[ns], acc[ms][ns], 0, 0, 0);
        }
    }
#undef K3_STAGE

    // C layout (32x32): col = lane&31, row = (reg&3) + 8*(reg>>2) + 4*half
#pragma unroll
    for (int ms = 0; ms < 2; ++ms) {
        const int rowb = ms * 32 + 4 * half;
#pragma unroll
        for (int ns = 0; ns < 2; ++ns) {
            const int col = i0 + ns * 32 + cl;
            if (col < DIM) {
#pragma unroll
                for (int q = 0; q < 4; ++q)
#pragma unroll
                    for (int j = 0; j < 4; ++j)
                        out[(size_t)(n0 + rowb + 8 * q + j) * DIM + col]
                            = acc[ms][ns][4 * q + j];
            }
        }
    }
}

extern "C" void kernel_launch(void* const* d_in, const int* in_sizes, int n_in,
                              void* d_out, int out_size, void* d_ws, size_t ws_size,
                              hipStream_t stream) {
    const float* F  = (const float*)d_in[0];   // (1024, 680)
    const float* D  = (const float*)d_in[1];   // (48, 24, 48, 680)
    const float* qw = (const float*)d_in[2];   // (24,)
    float* out = (float*)d_out;
    char*  ws  = (char*)d_ws;

    uint2* parts = (uint2*)ws;                                  // 27.0 MiB bf16
    const size_t parts_bytes = (size_t)SPLITS * NTILE * 16384 * 8;  // 28,311,552
    unsigned short* Mb = (unsigned short*)(ws + parts_bytes);   // 1.125 MiB
    const size_t mb_bytes = (size_t)DPAD * DPAD * 2;            // 1,179,648
    uint4* Fb = (uint4*)(ws + parts_bytes + mb_bytes);          // 1.5 MiB

    k12_gram<<<dim3(SPLITS * NTILE), 512, 0, stream>>>(D, qw, parts);
    kf_conv<<<dim3(1024 * DPAD / 8 / 256), 256, 0, stream>>>(F, Fb);
    k2_reduce<<<dim3(32, NTILE), 256, 0, stream>>>(parts, Mb);
    k3_mfma<<<dim3(16, 11), 64, 0, stream>>>(Fb, (const uint4*)Mb, out);
}